// Round 5
// baseline (323.016 us; speedup 1.0000x reference)
//
#include <hip/hip_runtime.h>
#include <hip/hip_bf16.h>

typedef unsigned int u32;
typedef _Float16 h2 __attribute__((ext_vector_type(2)));

#define TILE 16
#define HALO 18           // TILE + 2
#define NPIX (HALO*HALO)  // 324

// ================= ws layout (dword units) =================
// FNBP  [64][32] h2 pairs @ 0      : fnb[b][h-pair] = mb1 + fn@mw1[23:55]
// Weight pairs (h2) base  @ 2048:
#define W_SELF   0        // [10][32]  (mw1[c][2hp], mw1[c][2hp+1])
#define W_NBW    320      // [5][64]   (mw1[10+2q][h], mw1[11+2q][h])  c-pairs
#define W_WC     640      // [3][32]   (mw1[20+r][2hp], mw1[20+r][2hp+1])
#define W_MW2    736      // [10][32]  (mw2[2hp][c], mw2[2hp+1][c])
#define W_UB1    1056     // [32]      (ub1[2hp], ub1[2hp+1])
#define W_UW1    1088     // [20][32]  (uw1[c][2hp], uw1[c][2hp+1])
#define W_UW2    1728     // [10][32]  (uw2[2hp][c], uw2[2hp+1][c])
#define WS_W     2048
#define WS_SCAL  4096     // f32: mb2[0:10] ub2[10:20] gam[20:30] bet[30:40]
#define WS_DWORDS 4136    // 16544 bytes needed

// ---------------- helpers ----------------
__device__ __forceinline__ h2 pkrtz(float a, float b) {
    return __builtin_bit_cast(h2, __builtin_amdgcn_cvt_pkrtz(a, b));
}
#if __has_builtin(__builtin_elementwise_fma)
__device__ __forceinline__ h2 pkfma(h2 a, h2 b, h2 c) { return __builtin_elementwise_fma(a, b, c); }
#else
extern "C" __device__ h2 __ocml_fma_2f16(h2, h2, h2);
__device__ __forceinline__ h2 pkfma(h2 a, h2 b, h2 c) { return __ocml_fma_2f16(a, b, c); }
#endif
__device__ __forceinline__ float dot2f(h2 a, h2 b, float c) {
#if __has_builtin(__builtin_amdgcn_fdot2)
    return __builtin_amdgcn_fdot2(__builtin_bit_cast(__attribute__((ext_vector_type(2))) __fp16, a),
                                  __builtin_bit_cast(__attribute__((ext_vector_type(2))) __fp16, b),
                                  c, false);
#else
    return fmaf((float)a.x, (float)b.x, fmaf((float)a.y, (float)b.y, c));  // 2x v_fma_mix_f32
#endif
}
__device__ __forceinline__ h2 relu2(h2 v) {
    h2 z = (h2)(_Float16)0;
#if __has_builtin(__builtin_elementwise_max)
    return __builtin_elementwise_max(v, z);
#else
    h2 r;
    r.x = v.x > (_Float16)0 ? v.x : (_Float16)0;
    r.y = v.y > (_Float16)0 ? v.y : (_Float16)0;
    return r;
#endif
}
__device__ __forceinline__ h2 h2cast(u32 v) { return __builtin_bit_cast(h2, v); }

// ---------- prep: fnb per batch + f16-pair weight repack into ws ----------
// Distributed repack: block b handles entries [b*32, b*32+32) with threads 32..63.
__global__ __launch_bounds__(64) void prep_kernel(
    const float* __restrict__ fn,  const float* __restrict__ mw1, const float* __restrict__ mb1,
    const float* __restrict__ mw2, const float* __restrict__ mb2, const float* __restrict__ uw1,
    const float* __restrict__ ub1, const float* __restrict__ uw2, const float* __restrict__ ub2,
    const float* __restrict__ gam, const float* __restrict__ bet, u32* __restrict__ ws)
{
    const int b = blockIdx.x, t = threadIdx.x;
    h2* wh = (h2*)ws;
    if (t < 32) {
        float a0 = mb1[2*t], a1 = mb1[2*t+1];
        #pragma unroll 8
        for (int f = 0; f < 32; f++) {
            float fv = fn[b*32 + f];
            a0 += fv * mw1[(23+f)*64 + 2*t];
            a1 += fv * mw1[(23+f)*64 + 2*t+1];
        }
        wh[b*32 + t] = pkrtz(a0, a1);
    } else {
        const int i = b*32 + (t - 32);   // 64 blocks x 32 = 2048 entries, bijective
        float a, c; int j;
        if      (i < 320)  { int cc = i>>5,  hp = i&31;  a = mw1[cc*64 + 2*hp];       c = mw1[cc*64 + 2*hp+1]; }
        else if (i < 640)  { j = i-320;  int q = j>>6, hh = j&63; a = mw1[(10+2*q)*64 + hh]; c = mw1[(11+2*q)*64 + hh]; }
        else if (i < 736)  { j = i-640;  int r = j>>5, hp = j&31; a = mw1[(20+r)*64 + 2*hp]; c = mw1[(20+r)*64 + 2*hp+1]; }
        else if (i < 1056) { j = i-736;  int cc = j>>5, hp = j&31; a = mw2[(2*hp)*10 + cc];  c = mw2[(2*hp+1)*10 + cc]; }
        else if (i < 1088) { j = i-1056; a = ub1[2*j]; c = ub1[2*j+1]; }
        else if (i < 1728) { j = i-1088; int cc = j>>5, hp = j&31; a = uw1[cc*64 + 2*hp];    c = uw1[cc*64 + 2*hp+1]; }
        else               { j = i-1728; int cc = j>>5, hp = j&31; a = uw2[(2*hp)*10 + cc];  c = uw2[(2*hp+1)*10 + cc]; }
        wh[WS_W + i] = pkrtz(a, c);
    }
    if (b == 0 && t < 40) {
        float v;
        if      (t < 10) v = mb2[t];
        else if (t < 20) v = ub2[t-10];
        else if (t < 30) v = gam[t-20];
        else             v = bet[t-30];
        ((float*)ws)[WS_SCAL + t] = v;
    }
}

// ---------- main fused kernel ----------
// R0 structure (measured minimum VALU-issue: ~118 us): 256 threads, beliefs
// staged once, ONE 32-hp pass over nbp + per-pixel compute. Chunk-major nbp
// [8 chunks][NPIX][4 u32] = 41472 B (16B-aligned quads; write at p*16B,
// reads spread evenly across bank groups). LDS total 47952 B -> 3 blocks/CU.
// hp-splitting (time: R1/R3, wave: R4) measured strictly worse: +10-25 us of
// issued work vs the occupancy it buys. Do not re-split.
__global__ __launch_bounds__(256, 3) void mp_kernel(
    const float* __restrict__ beliefs, const float* __restrict__ cons,
    const u32* __restrict__ ws, float* __restrict__ out)
{
    __shared__ h2 bel_s[NPIX*5];                    // 6480 B, [pixel][c-pair]
    __shared__ __align__(16) u32 nbp_u[8*NPIX*4];   // 41472 B, [chunk][pixel][4]

    const int tid = threadIdx.x;
    const int b = blockIdx.z, y0 = blockIdx.y*TILE, x0 = blockIdx.x*TILE;

    const h2* Wfnb = (const h2*)ws;               // [64][32]
    const h2* W    = ((const h2*)ws) + WS_W;
    const float* SC = ((const float*)ws) + WS_SCAL;

    // ---- stage beliefs c-pairs with replicate halo ----
    for (int i = tid; i < NPIX*5; i += 256) {
        int p = i/5, q = i - p*5;
        int py = p/HALO, px = p - py*HALO;
        int gy = y0-1+py; gy = gy<0?0:(gy>127?127:gy);
        int gx = x0-1+px; gx = gx<0?0:(gx>127?127:gx);
        const float2 v = *(const float2*)(beliefs + (size_t)((b*128+gy)*128+gx)*10 + 2*q);
        bel_s[i] = pkrtz(v.x, v.y);
    }

    // ---- per-pixel state (independent of LDS; overlaps staging latency) ----
    const int tx = tid & 15, ty = tid >> 4;
    const int pc = (ty+1)*HALO + (tx+1);
    const size_t gpix = (size_t)((b*128 + (y0+ty))*128 + (x0+tx));

    int pnb[8];
    {
        const int doff[8] = {-19,-18,-17,-1,1,17,18,19};
        #pragma unroll
        for (int k = 0; k < 8; k++) pnb[k] = pc + doff[k];
    }

    float bel[10]; h2 beld[10];
    {
        const float2* bp = (const float2*)(beliefs + gpix*10);
        #pragma unroll
        for (int q = 0; q < 5; q++) {
            float2 v = bp[q];
            bel[2*q] = v.x; bel[2*q+1] = v.y;
            beld[2*q]   = pkrtz(v.x, v.x);
            beld[2*q+1] = pkrtz(v.y, v.y);
        }
    }
    h2 cond[24];
    {
        const float4* cp = (const float4*)(cons + gpix*24);
        #pragma unroll
        for (int r = 0; r < 6; r++) {
            float4 v = cp[r];
            cond[4*r+0] = pkrtz(v.x, v.x);
            cond[4*r+1] = pkrtz(v.y, v.y);
            cond[4*r+2] = pkrtz(v.z, v.z);
            cond[4*r+3] = pkrtz(v.w, v.w);
        }
    }

    __syncthreads();   // bel_s ready

    // ---- nbp[cl][p] = bel[p] @ mw1[10:20], all 32 hp in one pass ----
    for (int p = tid; p < NPIX; p += 256) {
        h2 bc[5];
        #pragma unroll
        for (int q = 0; q < 5; q++) bc[q] = bel_s[p*5 + q];
        #pragma unroll
        for (int cl = 0; cl < 8; cl++) {
            u32 ov[4];
            #pragma unroll
            for (int j = 0; j < 4; j++) {
                const int hp = cl*4 + j;
                float a0 = 0.f, a1 = 0.f;
                #pragma unroll
                for (int q = 0; q < 5; q++) {
                    a0 = dot2f(bc[q], W[W_NBW + q*64 + 2*hp],     a0);
                    a1 = dot2f(bc[q], W[W_NBW + q*64 + 2*hp + 1], a1);
                }
                ov[j] = __builtin_bit_cast(u32, pkrtz(a0, a1));
            }
            *(uint4*)(nbp_u + ((cl*NPIX + p) << 2)) = make_uint4(ov[0], ov[1], ov[2], ov[3]);
        }
    }
    __syncthreads();   // nbp ready

    // ---- per-pixel fused compute: hp chunks of 4, one b128 per (k, chunk) ----
    float acc2[10];
    #pragma unroll
    for (int c = 0; c < 10; c++) acc2[c] = 0.f;

    #pragma unroll 2
    for (int ch = 0; ch < 8; ch++) {
        const int hb = 4*ch;
        h2 t01[4], s01[4];
        #pragma unroll
        for (int j = 0; j < 4; j++) { t01[j] = Wfnb[b*32 + hb + j]; s01[j] = (h2)(_Float16)0; }
        #pragma unroll
        for (int c = 0; c < 10; c++) {
            #pragma unroll
            for (int j = 0; j < 4; j++)
                t01[j] = pkfma(beld[c], W[W_SELF + c*32 + hb + j], t01[j]);
        }
        h2 wc0[4], wc1[4], wc2[4];
        #pragma unroll
        for (int j = 0; j < 4; j++) {
            wc0[j] = W[W_WC      + hb + j];
            wc1[j] = W[W_WC + 32 + hb + j];
            wc2[j] = W[W_WC + 64 + hb + j];
        }
        #pragma unroll
        for (int k = 0; k < 8; k++) {
            const uint4 nv = *(const uint4*)(nbp_u + ((ch*NPIX + pnb[k]) << 2));
            const h2 nb[4] = { h2cast(nv.x), h2cast(nv.y), h2cast(nv.z), h2cast(nv.w) };
            const h2 c0 = cond[k*3+0], c1 = cond[k*3+1], c2 = cond[k*3+2];
            #pragma unroll
            for (int j = 0; j < 4; j++) {
                h2 v = t01[j] + nb[j];
                v = pkfma(c0, wc0[j], v);
                v = pkfma(c1, wc1[j], v);
                v = pkfma(c2, wc2[j], v);
                s01[j] += relu2(v);
            }
        }
        #pragma unroll
        for (int c = 0; c < 10; c++) {
            #pragma unroll
            for (int j = 0; j < 4; j++)
                acc2[c] = dot2f(s01[j], W[W_MW2 + c*32 + hb + j], acc2[c]);
        }
    }

    // agg = mean + mb2, duplicated-f16
    h2 aggd[10];
    #pragma unroll
    for (int c = 0; c < 10; c++) {
        float a = acc2[c]*0.125f + SC[c];
        aggd[c] = pkrtz(a, a);
    }

    float od[10];
    #pragma unroll
    for (int c = 0; c < 10; c++) od[c] = 0.f;

    #pragma unroll 4
    for (int hp = 0; hp < 32; hp++) {
        h2 u01 = W[W_UB1 + hp];
        #pragma unroll
        for (int c = 0; c < 10; c++) u01 = pkfma(beld[c], W[W_UW1 + c*32 + hp], u01);
        #pragma unroll
        for (int c = 0; c < 10; c++) u01 = pkfma(aggd[c], W[W_UW1 + (10+c)*32 + hp], u01);
        u01 = relu2(u01);
        #pragma unroll
        for (int c = 0; c < 10; c++) od[c] = dot2f(u01, W[W_UW2 + c*32 + hp], od[c]);
    }

    float x[10], mu = 0.f;
    #pragma unroll
    for (int c = 0; c < 10; c++) { x[c] = bel[c] + 0.5f*(od[c] + SC[10+c]); mu += x[c]; }
    mu *= 0.1f;
    float var = 0.f;
    #pragma unroll
    for (int c = 0; c < 10; c++) { float d = x[c] - mu; var += d*d; }
    var *= 0.1f;
    const float rs = rsqrtf(var + 1e-5f);

    float2* op = (float2*)(out + gpix*10);
    #pragma unroll
    for (int q = 0; q < 5; q++) {
        float2 r;
        r.x = (x[2*q]   - mu)*rs*SC[20+2*q]   + SC[30+2*q];
        r.y = (x[2*q+1] - mu)*rs*SC[20+2*q+1] + SC[30+2*q+1];
        op[q] = r;
    }
}

// ================== fallback (proven kernel, fp32 inputs) ==================
__device__ __forceinline__ float bf_lo(u32 v) { return __uint_as_float(v << 16); }
__device__ __forceinline__ float bf_hi(u32 v) { return __uint_as_float(v & 0xffff0000u); }
__device__ __forceinline__ u32 f2bf(float f) {
    u32 u = __float_as_uint(f);
    return (u + 0x7fffu + ((u >> 16) & 1u)) >> 16;
}
__device__ __forceinline__ u32 pack2(float a, float b) { return f2bf(a) | (f2bf(b) << 16); }
__device__ __forceinline__ u32 fpair(const float* a, int pi) { return pack2(a[2*pi], a[2*pi+1]); }

#define FW_MW2 736
#define FW_MB2 1056
#define FW_UW1 1061
#define FW_UB1 1701
#define FW_UW2 1733
#define FW_UB2 2053
#define FW_GAM 2058
#define FW_BET 2063
#define FW_TOT 2068

__global__ __launch_bounds__(256) void fallback_kernel(
    const float* __restrict__ beliefs, const float* __restrict__ cons, const float* __restrict__ fn,
    const float* __restrict__ mw1, const float* __restrict__ mb1, const float* __restrict__ mw2,
    const float* __restrict__ mb2, const float* __restrict__ uw1, const float* __restrict__ ub1,
    const float* __restrict__ uw2, const float* __restrict__ ub2, const float* __restrict__ gam,
    const float* __restrict__ bet, float* __restrict__ out)
{
    __shared__ float bel_s[NPIX*10];
    __shared__ u32   nbp_s[32*NPIX];
    __shared__ u32   w_s[FW_TOT];
    __shared__ float fnb_s[64];

    const int tid = threadIdx.x;
    const int b  = blockIdx.z;
    const int y0 = blockIdx.y * TILE;
    const int x0 = blockIdx.x * TILE;

    for (int i = tid; i < FW_TOT; i += 256) {
        u32 v;
        if      (i < 736)  v = fpair(mw1, i);
        else if (i < 1056) v = fpair(mw2, i - 736);
        else if (i < 1061) v = fpair(mb2, i - 1056);
        else if (i < 1701) v = fpair(uw1, i - 1061);
        else if (i < 1733) v = fpair(ub1, i - 1701);
        else if (i < 2053) v = fpair(uw2, i - 1733);
        else if (i < 2058) v = fpair(ub2, i - 2053);
        else if (i < 2063) v = fpair(gam, i - 2058);
        else               v = fpair(bet, i - 2063);
        w_s[i] = v;
    }
    if (tid < 64) {
        float acc = mb1[tid];
        #pragma unroll 8
        for (int f = 0; f < 32; f++)
            acc += fn[b*32 + f] * mw1[(23 + f)*64 + tid];
        fnb_s[tid] = acc;
    }
    for (int idx = tid; idx < NPIX*10; idx += 256) {
        int p = idx/10, c = idx - p*10;
        int py = p/HALO, px = p - py*HALO;
        int gy = y0-1+py; gy = gy<0?0:(gy>127?127:gy);
        int gx = x0-1+px; gx = gx<0?0:(gx>127?127:gx);
        bel_s[idx] = beliefs[((size_t)(b*128+gy)*128+gx)*10 + c];
    }
    __syncthreads();

    for (int p = tid; p < NPIX; p += 256) {
        float bl[10];
        #pragma unroll
        for (int c = 0; c < 10; c++) bl[c] = bel_s[p*10 + c];
        #pragma unroll 4
        for (int hp = 0; hp < 32; hp++) {
            float t0 = 0.f, t1 = 0.f;
            #pragma unroll
            for (int c = 0; c < 10; c++) {
                u32 wv = w_s[(10 + c)*32 + hp];
                t0 += bl[c] * bf_lo(wv);
                t1 += bl[c] * bf_hi(wv);
            }
            nbp_s[hp*NPIX + p] = pack2(t0, t1);
        }
    }
    __syncthreads();

    const int tx = tid & 15, ty = tid >> 4;
    const int pc = (ty + 1)*HALO + (tx + 1);
    float bel[10];
    #pragma unroll
    for (int c = 0; c < 10; c++) bel[c] = bel_s[pc*10 + c];
    const size_t gpix = (size_t)(b*128 + (y0 + ty))*128 + (x0 + tx);
    float con[24];
    #pragma unroll
    for (int j = 0; j < 24; j++) con[j] = cons[gpix*24 + j];

    float acc2[10];
    #pragma unroll
    for (int c = 0; c < 10; c++) acc2[c] = 0.f;

    #pragma unroll 2
    for (int hp = 0; hp < 32; hp++) {
        const int h0 = 2*hp, h1 = h0 + 1;
        float t0 = fnb_s[h0], t1 = fnb_s[h1];
        #pragma unroll
        for (int c = 0; c < 10; c++) {
            u32 wv = w_s[c*32 + hp];
            t0 += bel[c] * bf_lo(wv);
            t1 += bel[c] * bf_hi(wv);
        }
        const u32 wc0 = w_s[20*32 + hp], wc1 = w_s[21*32 + hp], wc2 = w_s[22*32 + hp];
        const u32* nbb = nbp_s + hp*NPIX + pc - 19;
        float s0 = 0.f, s1 = 0.f;
        #pragma unroll
        for (int k = 0; k < 8; k++) {
            const int doff[8] = { 0, 1, 2, 18, 20, 36, 37, 38 };
            u32 nv = nbb[doff[k]];
            float c0 = con[k*3], c1 = con[k*3+1], c2 = con[k*3+2];
            float v0 = t0 + bf_lo(nv) + c0*bf_lo(wc0) + c1*bf_lo(wc1) + c2*bf_lo(wc2);
            float v1 = t1 + bf_hi(nv) + c0*bf_hi(wc0) + c1*bf_hi(wc1) + c2*bf_hi(wc2);
            s0 += fmaxf(v0, 0.f);
            s1 += fmaxf(v1, 0.f);
        }
        #pragma unroll
        for (int cq = 0; cq < 5; cq++) {
            u32 a0 = w_s[FW_MW2 + h0*5 + cq];
            u32 a1 = w_s[FW_MW2 + h1*5 + cq];
            acc2[2*cq]   += s0*bf_lo(a0) + s1*bf_lo(a1);
            acc2[2*cq+1] += s0*bf_hi(a0) + s1*bf_hi(a1);
        }
    }

    float agg[10];
    #pragma unroll
    for (int cq = 0; cq < 5; cq++) {
        u32 bp = w_s[FW_MB2 + cq];
        agg[2*cq]   = acc2[2*cq]  *0.125f + bf_lo(bp);
        agg[2*cq+1] = acc2[2*cq+1]*0.125f + bf_hi(bp);
    }

    float od[10];
    #pragma unroll
    for (int c = 0; c < 10; c++) od[c] = 0.f;
    #pragma unroll 2
    for (int hp = 0; hp < 32; hp++) {
        u32 ubp = w_s[FW_UB1 + hp];
        float u0 = bf_lo(ubp), u1 = bf_hi(ubp);
        #pragma unroll
        for (int c = 0; c < 10; c++) {
            u32 wv = w_s[FW_UW1 + c*32 + hp];
            u0 += bel[c] * bf_lo(wv);
            u1 += bel[c] * bf_hi(wv);
        }
        #pragma unroll
        for (int c = 0; c < 10; c++) {
            u32 wv = w_s[FW_UW1 + (10 + c)*32 + hp];
            u0 += agg[c] * bf_lo(wv);
            u1 += agg[c] * bf_hi(wv);
        }
        u0 = fmaxf(u0, 0.f); u1 = fmaxf(u1, 0.f);
        const int h0 = 2*hp, h1 = h0 + 1;
        #pragma unroll
        for (int cq = 0; cq < 5; cq++) {
            u32 a0 = w_s[FW_UW2 + h0*5 + cq];
            u32 a1 = w_s[FW_UW2 + h1*5 + cq];
            od[2*cq]   += u0*bf_lo(a0) + u1*bf_lo(a1);
            od[2*cq+1] += u0*bf_hi(a0) + u1*bf_hi(a1);
        }
    }

    float x[10], mu = 0.f;
    #pragma unroll
    for (int cq = 0; cq < 5; cq++) {
        u32 bp = w_s[FW_UB2 + cq];
        x[2*cq]   = bel[2*cq]   + 0.5f*(od[2*cq]   + bf_lo(bp));
        x[2*cq+1] = bel[2*cq+1] + 0.5f*(od[2*cq+1] + bf_hi(bp));
        mu += x[2*cq] + x[2*cq+1];
    }
    mu *= 0.1f;
    float var = 0.f;
    #pragma unroll
    for (int c = 0; c < 10; c++) { float d = x[c] - mu; var += d*d; }
    var *= 0.1f;
    const float rs = rsqrtf(var + 1e-5f);

    float2* op = reinterpret_cast<float2*>(out + gpix*10);
    #pragma unroll
    for (int q = 0; q < 5; q++) {
        u32 gp = w_s[FW_GAM + q], bq = w_s[FW_BET + q];
        float2 r;
        r.x = (x[2*q]   - mu)*rs*bf_lo(gp) + bf_lo(bq);
        r.y = (x[2*q+1] - mu)*rs*bf_hi(gp) + bf_hi(bq);
        op[q] = r;
    }
}

extern "C" void kernel_launch(void* const* d_in, const int* in_sizes, int n_in,
                              void* d_out, int out_size, void* d_ws, size_t ws_size,
                              hipStream_t stream) {
    (void)in_sizes; (void)n_in; (void)out_size;
    const float* beliefs = (const float*)d_in[0];
    const float* cons    = (const float*)d_in[1];
    const float* fn      = (const float*)d_in[2];
    const float* mw1     = (const float*)d_in[3];
    const float* mb1     = (const float*)d_in[4];
    const float* mw2     = (const float*)d_in[5];
    const float* mb2     = (const float*)d_in[6];
    const float* uw1     = (const float*)d_in[7];
    const float* ub1     = (const float*)d_in[8];
    const float* uw2     = (const float*)d_in[9];
    const float* ub2     = (const float*)d_in[10];
    const float* gam     = (const float*)d_in[11];
    const float* bet     = (const float*)d_in[12];
    float* outp = (float*)d_out;

    if (ws_size >= (size_t)WS_DWORDS*4) {
        prep_kernel<<<dim3(64), dim3(64), 0, stream>>>(
            fn, mw1, mb1, mw2, mb2, uw1, ub1, uw2, ub2, gam, bet, (u32*)d_ws);
        mp_kernel<<<dim3(8, 8, 64), dim3(256), 0, stream>>>(
            beliefs, cons, (const u32*)d_ws, outp);
    } else {
        fallback_kernel<<<dim3(8, 8, 64), dim3(256), 0, stream>>>(
            beliefs, cons, fn, mw1, mb1, mw2, mb2, uw1, ub1, uw2, ub2, gam, bet, outp);
    }
}

// Round 6
// 294.970 us; speedup vs baseline: 1.0951x; 1.0951x over previous
//
#include <hip/hip_runtime.h>
#include <hip/hip_bf16.h>

typedef unsigned int u32;
typedef _Float16 h2 __attribute__((ext_vector_type(2)));

#define TILE 16
#define HALO 18           // TILE + 2
#define NPIX (HALO*HALO)  // 324

// ================= ws layout (dword units) =================
// FNBP  [64][32] h2 pairs @ 0      : fnb[b][h-pair] = mb1 + fn@mw1[23:55]
// Weight pairs (h2) base  @ 2048:
#define W_SELF   0        // [10][32]  (mw1[c][2hp], mw1[c][2hp+1])
#define W_NBW    320      // [5][64]   (mw1[10+2q][h], mw1[11+2q][h])  c-pairs
#define W_WC     640      // [3][32]   (mw1[20+r][2hp], mw1[20+r][2hp+1])
#define W_MW2    736      // [10][32]  (mw2[2hp][c], mw2[2hp+1][c])
#define W_UB1    1056     // [32]      (ub1[2hp], ub1[2hp+1])
#define W_UW1    1088     // [20][32]  (uw1[c][2hp], uw1[c][2hp+1])
#define W_UW2    1728     // [10][32]  (uw2[2hp][c], uw2[2hp+1][c])
#define WS_W     2048
#define WS_SCAL  4096     // f32: mb2[0:10] ub2[10:20] gam[20:30] bet[30:40]
#define WS_DWORDS 4136    // 16544 bytes needed

// ---------------- helpers ----------------
__device__ __forceinline__ h2 pkrtz(float a, float b) {
    return __builtin_bit_cast(h2, __builtin_amdgcn_cvt_pkrtz(a, b));
}
#if __has_builtin(__builtin_elementwise_fma)
__device__ __forceinline__ h2 pkfma(h2 a, h2 b, h2 c) { return __builtin_elementwise_fma(a, b, c); }
#else
extern "C" __device__ h2 __ocml_fma_2f16(h2, h2, h2);
__device__ __forceinline__ h2 pkfma(h2 a, h2 b, h2 c) { return __ocml_fma_2f16(a, b, c); }
#endif
__device__ __forceinline__ float dot2f(h2 a, h2 b, float c) {
#if __has_builtin(__builtin_amdgcn_fdot2)
    return __builtin_amdgcn_fdot2(__builtin_bit_cast(__attribute__((ext_vector_type(2))) __fp16, a),
                                  __builtin_bit_cast(__attribute__((ext_vector_type(2))) __fp16, b),
                                  c, false);
#else
    return fmaf((float)a.x, (float)b.x, fmaf((float)a.y, (float)b.y, c));  // 2x v_fma_mix_f32
#endif
}
__device__ __forceinline__ h2 relu2(h2 v) {
    h2 z = (h2)(_Float16)0;
#if __has_builtin(__builtin_elementwise_max)
    return __builtin_elementwise_max(v, z);
#else
    h2 r;
    r.x = v.x > (_Float16)0 ? v.x : (_Float16)0;
    r.y = v.y > (_Float16)0 ? v.y : (_Float16)0;
    return r;
#endif
}
__device__ __forceinline__ h2 h2cast(u32 v) { return __builtin_bit_cast(h2, v); }

// ---------- prep: fnb per batch + f16-pair weight repack into ws ----------
// Distributed repack: block b handles entries [b*32, b*32+32) with threads 32..63.
__global__ __launch_bounds__(64) void prep_kernel(
    const float* __restrict__ fn,  const float* __restrict__ mw1, const float* __restrict__ mb1,
    const float* __restrict__ mw2, const float* __restrict__ mb2, const float* __restrict__ uw1,
    const float* __restrict__ ub1, const float* __restrict__ uw2, const float* __restrict__ ub2,
    const float* __restrict__ gam, const float* __restrict__ bet, u32* __restrict__ ws)
{
    const int b = blockIdx.x, t = threadIdx.x;
    h2* wh = (h2*)ws;
    if (t < 32) {
        float a0 = mb1[2*t], a1 = mb1[2*t+1];
        #pragma unroll 8
        for (int f = 0; f < 32; f++) {
            float fv = fn[b*32 + f];
            a0 += fv * mw1[(23+f)*64 + 2*t];
            a1 += fv * mw1[(23+f)*64 + 2*t+1];
        }
        wh[b*32 + t] = pkrtz(a0, a1);
    } else {
        const int i = b*32 + (t - 32);   // 64 blocks x 32 = 2048 entries, bijective
        float a, c; int j;
        if      (i < 320)  { int cc = i>>5,  hp = i&31;  a = mw1[cc*64 + 2*hp];       c = mw1[cc*64 + 2*hp+1]; }
        else if (i < 640)  { j = i-320;  int q = j>>6, hh = j&63; a = mw1[(10+2*q)*64 + hh]; c = mw1[(11+2*q)*64 + hh]; }
        else if (i < 736)  { j = i-640;  int r = j>>5, hp = j&31; a = mw1[(20+r)*64 + 2*hp]; c = mw1[(20+r)*64 + 2*hp+1]; }
        else if (i < 1056) { j = i-736;  int cc = j>>5, hp = j&31; a = mw2[(2*hp)*10 + cc];  c = mw2[(2*hp+1)*10 + cc]; }
        else if (i < 1088) { j = i-1056; a = ub1[2*j]; c = ub1[2*j+1]; }
        else if (i < 1728) { j = i-1088; int cc = j>>5, hp = j&31; a = uw1[cc*64 + 2*hp];    c = uw1[cc*64 + 2*hp+1]; }
        else               { j = i-1728; int cc = j>>5, hp = j&31; a = uw2[(2*hp)*10 + cc];  c = uw2[(2*hp+1)*10 + cc]; }
        wh[WS_W + i] = pkrtz(a, c);
    }
    if (b == 0 && t < 40) {
        float v;
        if      (t < 10) v = mb2[t];
        else if (t < 20) v = ub2[t-10];
        else if (t < 30) v = gam[t-20];
        else             v = bet[t-30];
        ((float*)ws)[WS_SCAL + t] = v;
    }
}

// ---------- main fused kernel ----------
// Best-measured structure (R1, bench 310.6): 256 threads, hidden dim in 2
// time-phases of 16 hp, nbp chunk-major [4][NPIX][4 u32] = 20736 B recycled
// between halves -> 7 blocks/CU ceiling. Improvement over R1: each thread's
// 1-2 staging pixels' beliefs are loaded ONCE into registers (bcA/bcB) and
// reused by both halves -- removes R1's duplicated global load+clamp+cvt.
// All weight indices compile-time (unrolled half/cl/j/c). LDS accesses use
// explicit byte bases + literal chunk offsets (ds offset immediates).
__global__ __launch_bounds__(256, 6) void mp_kernel(
    const float* __restrict__ beliefs, const float* __restrict__ cons,
    const u32* __restrict__ ws, float* __restrict__ out)
{
    __shared__ __align__(16) u32 nbp_u[4*NPIX*4];   // 20736 B, [chunk][pixel][4]

    const int tid = threadIdx.x;
    const int b = blockIdx.z, y0 = blockIdx.y*TILE, x0 = blockIdx.x*TILE;

    const h2* Wfnb = (const h2*)ws;               // [64][32]
    const h2* W    = ((const h2*)ws) + WS_W;
    const float* SC = ((const float*)ws) + WS_SCAL;

    // ---- load staging pixels' beliefs ONCE into registers ----
    h2 bcA[5], bcB[5] = {};
    {
        const int p = tid;
        int py = p/HALO, px = p - py*HALO;
        int gy = y0-1+py; gy = gy<0?0:(gy>127?127:gy);
        int gx = x0-1+px; gx = gx<0?0:(gx>127?127:gx);
        const float2* bp = (const float2*)(beliefs + (size_t)((b*128+gy)*128+gx)*10);
        #pragma unroll
        for (int q = 0; q < 5; q++) { float2 v = bp[q]; bcA[q] = pkrtz(v.x, v.y); }
    }
    const bool hasB = tid < (NPIX - 256);   // tid < 68
    if (hasB) {
        const int p = tid + 256;
        int py = p/HALO, px = p - py*HALO;
        int gy = y0-1+py; gy = gy<0?0:(gy>127?127:gy);
        int gx = x0-1+px; gx = gx<0?0:(gx>127?127:gx);
        const float2* bp = (const float2*)(beliefs + (size_t)((b*128+gy)*128+gx)*10);
        #pragma unroll
        for (int q = 0; q < 5; q++) { float2 v = bp[q]; bcB[q] = pkrtz(v.x, v.y); }
    }

    // ---- per-pixel state ----
    const int tx = tid & 15, ty = tid >> 4;
    const int pc = (ty+1)*HALO + (tx+1);
    const size_t gpix = (size_t)((b*128 + (y0+ty))*128 + (x0+tx));

    u32 kb[8];   // byte bases of the 8 neighbors' nbp rows
    {
        const int doff[8] = {-19,-18,-17,-1,1,17,18,19};
        #pragma unroll
        for (int k = 0; k < 8; k++) kb[k] = (u32)(pc + doff[k]) * 16u;
    }

    float bel[10]; h2 beld[10];
    {
        const float2* bp = (const float2*)(beliefs + gpix*10);
        #pragma unroll
        for (int q = 0; q < 5; q++) {
            float2 v = bp[q];
            bel[2*q] = v.x; bel[2*q+1] = v.y;
            beld[2*q]   = pkrtz(v.x, v.x);
            beld[2*q+1] = pkrtz(v.y, v.y);
        }
    }
    h2 cond[24];
    {
        const float4* cp = (const float4*)(cons + gpix*24);
        #pragma unroll
        for (int r = 0; r < 6; r++) {
            float4 v = cp[r];
            cond[4*r+0] = pkrtz(v.x, v.x);
            cond[4*r+1] = pkrtz(v.y, v.y);
            cond[4*r+2] = pkrtz(v.z, v.z);
            cond[4*r+3] = pkrtz(v.w, v.w);
        }
    }

    float acc2[10];
    #pragma unroll
    for (int c = 0; c < 10; c++) acc2[c] = 0.f;

    char* nbpB = (char*)nbp_u;

    #pragma unroll
    for (int half = 0; half < 2; half++) {
        if (half) __syncthreads();   // all reads of previous half's nbp done

        // ---- nbp[cl][p] = bel[p] @ mw1[10:20] for hp in [half*16, +16), from regs ----
        #pragma unroll
        for (int cl = 0; cl < 4; cl++) {
            uint4 ov;
            u32 t[4];
            #pragma unroll
            for (int j = 0; j < 4; j++) {
                const int hp = half*16 + cl*4 + j;   // literal
                float a0 = 0.f, a1 = 0.f;
                #pragma unroll
                for (int q = 0; q < 5; q++) {
                    a0 = dot2f(bcA[q], W[W_NBW + q*64 + 2*hp],     a0);
                    a1 = dot2f(bcA[q], W[W_NBW + q*64 + 2*hp + 1], a1);
                }
                t[j] = __builtin_bit_cast(u32, pkrtz(a0, a1));
            }
            ov.x = t[0]; ov.y = t[1]; ov.z = t[2]; ov.w = t[3];
            *(uint4*)(nbpB + (u32)tid*16u + cl*(NPIX*16)) = ov;
        }
        if (hasB) {
            #pragma unroll
            for (int cl = 0; cl < 4; cl++) {
                uint4 ov;
                u32 t[4];
                #pragma unroll
                for (int j = 0; j < 4; j++) {
                    const int hp = half*16 + cl*4 + j;
                    float a0 = 0.f, a1 = 0.f;
                    #pragma unroll
                    for (int q = 0; q < 5; q++) {
                        a0 = dot2f(bcB[q], W[W_NBW + q*64 + 2*hp],     a0);
                        a1 = dot2f(bcB[q], W[W_NBW + q*64 + 2*hp + 1], a1);
                    }
                    t[j] = __builtin_bit_cast(u32, pkrtz(a0, a1));
                }
                ov.x = t[0]; ov.y = t[1]; ov.z = t[2]; ov.w = t[3];
                *(uint4*)(nbpB + (u32)(tid + 256)*16u + cl*(NPIX*16)) = ov;
            }
        }
        __syncthreads();   // nbp ready

        // ---- message net for this half's 4 chunks ----
        #pragma unroll 2
        for (int cl = 0; cl < 4; cl++) {
            const int hb = half*16 + cl*4;   // literal
            h2 t01[4], s01[4];
            #pragma unroll
            for (int j = 0; j < 4; j++) { t01[j] = Wfnb[b*32 + hb + j]; s01[j] = (h2)(_Float16)0; }
            #pragma unroll
            for (int c = 0; c < 10; c++) {
                #pragma unroll
                for (int j = 0; j < 4; j++)
                    t01[j] = pkfma(beld[c], W[W_SELF + c*32 + hb + j], t01[j]);
            }
            h2 wc0[4], wc1[4], wc2[4];
            #pragma unroll
            for (int j = 0; j < 4; j++) {
                wc0[j] = W[W_WC      + hb + j];
                wc1[j] = W[W_WC + 32 + hb + j];
                wc2[j] = W[W_WC + 64 + hb + j];
            }
            #pragma unroll
            for (int k = 0; k < 8; k++) {
                const uint4 nv = *(const uint4*)(nbpB + kb[k] + cl*(NPIX*16));
                const h2 nb[4] = { h2cast(nv.x), h2cast(nv.y), h2cast(nv.z), h2cast(nv.w) };
                const h2 c0 = cond[k*3+0], c1 = cond[k*3+1], c2 = cond[k*3+2];
                #pragma unroll
                for (int j = 0; j < 4; j++) {
                    h2 v = t01[j] + nb[j];
                    v = pkfma(c0, wc0[j], v);
                    v = pkfma(c1, wc1[j], v);
                    v = pkfma(c2, wc2[j], v);
                    s01[j] += relu2(v);
                }
            }
            #pragma unroll
            for (int c = 0; c < 10; c++) {
                #pragma unroll
                for (int j = 0; j < 4; j++)
                    acc2[c] = dot2f(s01[j], W[W_MW2 + c*32 + hb + j], acc2[c]);
            }
        }
    }

    // agg = mean + mb2, duplicated-f16
    h2 aggd[10];
    #pragma unroll
    for (int c = 0; c < 10; c++) {
        float a = acc2[c]*0.125f + SC[c];
        aggd[c] = pkrtz(a, a);
    }

    float od[10];
    #pragma unroll
    for (int c = 0; c < 10; c++) od[c] = 0.f;

    #pragma unroll 4
    for (int hp = 0; hp < 32; hp++) {
        h2 u01 = W[W_UB1 + hp];
        #pragma unroll
        for (int c = 0; c < 10; c++) u01 = pkfma(beld[c], W[W_UW1 + c*32 + hp], u01);
        #pragma unroll
        for (int c = 0; c < 10; c++) u01 = pkfma(aggd[c], W[W_UW1 + (10+c)*32 + hp], u01);
        u01 = relu2(u01);
        #pragma unroll
        for (int c = 0; c < 10; c++) od[c] = dot2f(u01, W[W_UW2 + c*32 + hp], od[c]);
    }

    float x[10], mu = 0.f;
    #pragma unroll
    for (int c = 0; c < 10; c++) { x[c] = bel[c] + 0.5f*(od[c] + SC[10+c]); mu += x[c]; }
    mu *= 0.1f;
    float var = 0.f;
    #pragma unroll
    for (int c = 0; c < 10; c++) { float d = x[c] - mu; var += d*d; }
    var *= 0.1f;
    const float rs = rsqrtf(var + 1e-5f);

    float2* op = (float2*)(out + gpix*10);
    #pragma unroll
    for (int q = 0; q < 5; q++) {
        float2 r;
        r.x = (x[2*q]   - mu)*rs*SC[20+2*q]   + SC[30+2*q];
        r.y = (x[2*q+1] - mu)*rs*SC[20+2*q+1] + SC[30+2*q+1];
        op[q] = r;
    }
}

// ================== fallback (proven kernel, fp32 inputs) ==================
__device__ __forceinline__ float bf_lo(u32 v) { return __uint_as_float(v << 16); }
__device__ __forceinline__ float bf_hi(u32 v) { return __uint_as_float(v & 0xffff0000u); }
__device__ __forceinline__ u32 f2bf(float f) {
    u32 u = __float_as_uint(f);
    return (u + 0x7fffu + ((u >> 16) & 1u)) >> 16;
}
__device__ __forceinline__ u32 pack2(float a, float b) { return f2bf(a) | (f2bf(b) << 16); }
__device__ __forceinline__ u32 fpair(const float* a, int pi) { return pack2(a[2*pi], a[2*pi+1]); }

#define FW_MW2 736
#define FW_MB2 1056
#define FW_UW1 1061
#define FW_UB1 1701
#define FW_UW2 1733
#define FW_UB2 2053
#define FW_GAM 2058
#define FW_BET 2063
#define FW_TOT 2068

__global__ __launch_bounds__(256) void fallback_kernel(
    const float* __restrict__ beliefs, const float* __restrict__ cons, const float* __restrict__ fn,
    const float* __restrict__ mw1, const float* __restrict__ mb1, const float* __restrict__ mw2,
    const float* __restrict__ mb2, const float* __restrict__ uw1, const float* __restrict__ ub1,
    const float* __restrict__ uw2, const float* __restrict__ ub2, const float* __restrict__ gam,
    const float* __restrict__ bet, float* __restrict__ out)
{
    __shared__ float bel_s[NPIX*10];
    __shared__ u32   nbp_s[32*NPIX];
    __shared__ u32   w_s[FW_TOT];
    __shared__ float fnb_s[64];

    const int tid = threadIdx.x;
    const int b  = blockIdx.z;
    const int y0 = blockIdx.y * TILE;
    const int x0 = blockIdx.x * TILE;

    for (int i = tid; i < FW_TOT; i += 256) {
        u32 v;
        if      (i < 736)  v = fpair(mw1, i);
        else if (i < 1056) v = fpair(mw2, i - 736);
        else if (i < 1061) v = fpair(mb2, i - 1056);
        else if (i < 1701) v = fpair(uw1, i - 1061);
        else if (i < 1733) v = fpair(ub1, i - 1701);
        else if (i < 2053) v = fpair(uw2, i - 1733);
        else if (i < 2058) v = fpair(ub2, i - 2053);
        else if (i < 2063) v = fpair(gam, i - 2058);
        else               v = fpair(bet, i - 2063);
        w_s[i] = v;
    }
    if (tid < 64) {
        float acc = mb1[tid];
        #pragma unroll 8
        for (int f = 0; f < 32; f++)
            acc += fn[b*32 + f] * mw1[(23 + f)*64 + tid];
        fnb_s[tid] = acc;
    }
    for (int idx = tid; idx < NPIX*10; idx += 256) {
        int p = idx/10, c = idx - p*10;
        int py = p/HALO, px = p - py*HALO;
        int gy = y0-1+py; gy = gy<0?0:(gy>127?127:gy);
        int gx = x0-1+px; gx = gx<0?0:(gx>127?127:gx);
        bel_s[idx] = beliefs[((size_t)(b*128+gy)*128+gx)*10 + c];
    }
    __syncthreads();

    for (int p = tid; p < NPIX; p += 256) {
        float bl[10];
        #pragma unroll
        for (int c = 0; c < 10; c++) bl[c] = bel_s[p*10 + c];
        #pragma unroll 4
        for (int hp = 0; hp < 32; hp++) {
            float t0 = 0.f, t1 = 0.f;
            #pragma unroll
            for (int c = 0; c < 10; c++) {
                u32 wv = w_s[(10 + c)*32 + hp];
                t0 += bl[c] * bf_lo(wv);
                t1 += bl[c] * bf_hi(wv);
            }
            nbp_s[hp*NPIX + p] = pack2(t0, t1);
        }
    }
    __syncthreads();

    const int tx = tid & 15, ty = tid >> 4;
    const int pc = (ty + 1)*HALO + (tx + 1);
    float bel[10];
    #pragma unroll
    for (int c = 0; c < 10; c++) bel[c] = bel_s[pc*10 + c];
    const size_t gpix = (size_t)(b*128 + (y0 + ty))*128 + (x0 + tx);
    float con[24];
    #pragma unroll
    for (int j = 0; j < 24; j++) con[j] = cons[gpix*24 + j];

    float acc2[10];
    #pragma unroll
    for (int c = 0; c < 10; c++) acc2[c] = 0.f;

    #pragma unroll 2
    for (int hp = 0; hp < 32; hp++) {
        const int h0 = 2*hp, h1 = h0 + 1;
        float t0 = fnb_s[h0], t1 = fnb_s[h1];
        #pragma unroll
        for (int c = 0; c < 10; c++) {
            u32 wv = w_s[c*32 + hp];
            t0 += bel[c] * bf_lo(wv);
            t1 += bel[c] * bf_hi(wv);
        }
        const u32 wc0 = w_s[20*32 + hp], wc1 = w_s[21*32 + hp], wc2 = w_s[22*32 + hp];
        const u32* nbb = nbp_s + hp*NPIX + pc - 19;
        float s0 = 0.f, s1 = 0.f;
        #pragma unroll
        for (int k = 0; k < 8; k++) {
            const int doff[8] = { 0, 1, 2, 18, 20, 36, 37, 38 };
            u32 nv = nbb[doff[k]];
            float c0 = con[k*3], c1 = con[k*3+1], c2 = con[k*3+2];
            float v0 = t0 + bf_lo(nv) + c0*bf_lo(wc0) + c1*bf_lo(wc1) + c2*bf_lo(wc2);
            float v1 = t1 + bf_hi(nv) + c0*bf_hi(wc0) + c1*bf_hi(wc1) + c2*bf_hi(wc2);
            s0 += fmaxf(v0, 0.f);
            s1 += fmaxf(v1, 0.f);
        }
        #pragma unroll
        for (int cq = 0; cq < 5; cq++) {
            u32 a0 = w_s[FW_MW2 + h0*5 + cq];
            u32 a1 = w_s[FW_MW2 + h1*5 + cq];
            acc2[2*cq]   += s0*bf_lo(a0) + s1*bf_lo(a1);
            acc2[2*cq+1] += s0*bf_hi(a0) + s1*bf_hi(a1);
        }
    }

    float agg[10];
    #pragma unroll
    for (int cq = 0; cq < 5; cq++) {
        u32 bp = w_s[FW_MB2 + cq];
        agg[2*cq]   = acc2[2*cq]  *0.125f + bf_lo(bp);
        agg[2*cq+1] = acc2[2*cq+1]*0.125f + bf_hi(bp);
    }

    float od[10];
    #pragma unroll
    for (int c = 0; c < 10; c++) od[c] = 0.f;
    #pragma unroll 2
    for (int hp = 0; hp < 32; hp++) {
        u32 ubp = w_s[FW_UB1 + hp];
        float u0 = bf_lo(ubp), u1 = bf_hi(ubp);
        #pragma unroll
        for (int c = 0; c < 10; c++) {
            u32 wv = w_s[FW_UW1 + c*32 + hp];
            u0 += bel[c] * bf_lo(wv);
            u1 += bel[c] * bf_hi(wv);
        }
        #pragma unroll
        for (int c = 0; c < 10; c++) {
            u32 wv = w_s[FW_UW1 + (10 + c)*32 + hp];
            u0 += agg[c] * bf_lo(wv);
            u1 += agg[c] * bf_hi(wv);
        }
        u0 = fmaxf(u0, 0.f); u1 = fmaxf(u1, 0.f);
        const int h0 = 2*hp, h1 = h0 + 1;
        #pragma unroll
        for (int cq = 0; cq < 5; cq++) {
            u32 a0 = w_s[FW_UW2 + h0*5 + cq];
            u32 a1 = w_s[FW_UW2 + h1*5 + cq];
            od[2*cq]   += u0*bf_lo(a0) + u1*bf_lo(a1);
            od[2*cq+1] += u0*bf_hi(a0) + u1*bf_hi(a1);
        }
    }

    float x[10], mu = 0.f;
    #pragma unroll
    for (int cq = 0; cq < 5; cq++) {
        u32 bp = w_s[FW_UB2 + cq];
        x[2*cq]   = bel[2*cq]   + 0.5f*(od[2*cq]   + bf_lo(bp));
        x[2*cq+1] = bel[2*cq+1] + 0.5f*(od[2*cq+1] + bf_hi(bp));
        mu += x[2*cq] + x[2*cq+1];
    }
    mu *= 0.1f;
    float var = 0.f;
    #pragma unroll
    for (int c = 0; c < 10; c++) { float d = x[c] - mu; var += d*d; }
    var *= 0.1f;
    const float rs = rsqrtf(var + 1e-5f);

    float2* op = reinterpret_cast<float2*>(out + gpix*10);
    #pragma unroll
    for (int q = 0; q < 5; q++) {
        u32 gp = w_s[FW_GAM + q], bq = w_s[FW_BET + q];
        float2 r;
        r.x = (x[2*q]   - mu)*rs*bf_lo(gp) + bf_lo(bq);
        r.y = (x[2*q+1] - mu)*rs*bf_hi(gp) + bf_hi(bq);
        op[q] = r;
    }
}

extern "C" void kernel_launch(void* const* d_in, const int* in_sizes, int n_in,
                              void* d_out, int out_size, void* d_ws, size_t ws_size,
                              hipStream_t stream) {
    (void)in_sizes; (void)n_in; (void)out_size;
    const float* beliefs = (const float*)d_in[0];
    const float* cons    = (const float*)d_in[1];
    const float* fn      = (const float*)d_in[2];
    const float* mw1     = (const float*)d_in[3];
    const float* mb1     = (const float*)d_in[4];
    const float* mw2     = (const float*)d_in[5];
    const float* mb2     = (const float*)d_in[6];
    const float* uw1     = (const float*)d_in[7];
    const float* ub1     = (const float*)d_in[8];
    const float* uw2     = (const float*)d_in[9];
    const float* ub2     = (const float*)d_in[10];
    const float* gam     = (const float*)d_in[11];
    const float* bet     = (const float*)d_in[12];
    float* outp = (float*)d_out;

    if (ws_size >= (size_t)WS_DWORDS*4) {
        prep_kernel<<<dim3(64), dim3(64), 0, stream>>>(
            fn, mw1, mb1, mw2, mb2, uw1, ub1, uw2, ub2, gam, bet, (u32*)d_ws);
        mp_kernel<<<dim3(8, 8, 64), dim3(256), 0, stream>>>(
            beliefs, cons, (const u32*)d_ws, outp);
    } else {
        fallback_kernel<<<dim3(8, 8, 64), dim3(256), 0, stream>>>(
            beliefs, cons, fn, mw1, mb1, mw2, mb2, uw1, ub1, uw2, ub2, gam, bet, outp);
    }
}

// Round 7
// 294.482 us; speedup vs baseline: 1.0969x; 1.0017x over previous
//
#include <hip/hip_runtime.h>
#include <hip/hip_bf16.h>

typedef unsigned int u32;
typedef _Float16 h2 __attribute__((ext_vector_type(2)));

#define TILE 16
#define HALO 18           // TILE + 2
#define NPIX (HALO*HALO)  // 324

// ================= ws layout (dword units) =================
// FNBP  [64][32] h2 pairs @ 0      : fnb[b][h-pair] = mb1 + fn@mw1[23:55]
// Weight pairs (h2) base  @ 2048:
#define W_SELF   0        // [10][32]  (mw1[c][2hp], mw1[c][2hp+1])
#define W_NBW    320      // [5][64]   (mw1[10+2q][h], mw1[11+2q][h])  c-pairs
#define W_WC     640      // [3][32]   (mw1[20+r][2hp], mw1[20+r][2hp+1])
#define W_MW2    736      // [10][32]  (mw2[2hp][c], mw2[2hp+1][c])
#define W_UB1    1056     // [32]      (ub1[2hp], ub1[2hp+1])
#define W_UW1    1088     // [20][32]  (uw1[c][2hp], uw1[c][2hp+1])
#define W_UW2    1728     // [10][32]  (uw2[2hp][c], uw2[2hp+1][c])
#define WS_W     2048
#define WS_SCAL  4096     // f32: mb2[0:10] ub2[10:20] gam[20:30] bet[30:40]
#define WS_DWORDS 4136    // 16544 bytes needed

// ---------------- helpers ----------------
__device__ __forceinline__ h2 pkrtz(float a, float b) {
    return __builtin_bit_cast(h2, __builtin_amdgcn_cvt_pkrtz(a, b));
}
#if __has_builtin(__builtin_elementwise_fma)
__device__ __forceinline__ h2 pkfma(h2 a, h2 b, h2 c) { return __builtin_elementwise_fma(a, b, c); }
#else
extern "C" __device__ h2 __ocml_fma_2f16(h2, h2, h2);
__device__ __forceinline__ h2 pkfma(h2 a, h2 b, h2 c) { return __ocml_fma_2f16(a, b, c); }
#endif
__device__ __forceinline__ float dot2f(h2 a, h2 b, float c) {
#if __has_builtin(__builtin_amdgcn_fdot2)
    return __builtin_amdgcn_fdot2(__builtin_bit_cast(__attribute__((ext_vector_type(2))) __fp16, a),
                                  __builtin_bit_cast(__attribute__((ext_vector_type(2))) __fp16, b),
                                  c, false);
#else
    return fmaf((float)a.x, (float)b.x, fmaf((float)a.y, (float)b.y, c));  // 2x v_fma_mix_f32
#endif
}
__device__ __forceinline__ h2 relu2(h2 v) {
    h2 z = (h2)(_Float16)0;
#if __has_builtin(__builtin_elementwise_max)
    return __builtin_elementwise_max(v, z);
#else
    h2 r;
    r.x = v.x > (_Float16)0 ? v.x : (_Float16)0;
    r.y = v.y > (_Float16)0 ? v.y : (_Float16)0;
    return r;
#endif
}
__device__ __forceinline__ h2 h2cast(u32 v) { return __builtin_bit_cast(h2, v); }

// ---------- prep: fnb per batch + f16-pair weight repack into ws ----------
// Distributed repack: block b handles entries [b*32, b*32+32) with threads 32..63.
__global__ __launch_bounds__(64) void prep_kernel(
    const float* __restrict__ fn,  const float* __restrict__ mw1, const float* __restrict__ mb1,
    const float* __restrict__ mw2, const float* __restrict__ mb2, const float* __restrict__ uw1,
    const float* __restrict__ ub1, const float* __restrict__ uw2, const float* __restrict__ ub2,
    const float* __restrict__ gam, const float* __restrict__ bet, u32* __restrict__ ws)
{
    const int b = blockIdx.x, t = threadIdx.x;
    h2* wh = (h2*)ws;
    if (t < 32) {
        float a0 = mb1[2*t], a1 = mb1[2*t+1];
        #pragma unroll 8
        for (int f = 0; f < 32; f++) {
            float fv = fn[b*32 + f];
            a0 += fv * mw1[(23+f)*64 + 2*t];
            a1 += fv * mw1[(23+f)*64 + 2*t+1];
        }
        wh[b*32 + t] = pkrtz(a0, a1);
    } else {
        const int i = b*32 + (t - 32);   // 64 blocks x 32 = 2048 entries, bijective
        float a, c; int j;
        if      (i < 320)  { int cc = i>>5,  hp = i&31;  a = mw1[cc*64 + 2*hp];       c = mw1[cc*64 + 2*hp+1]; }
        else if (i < 640)  { j = i-320;  int q = j>>6, hh = j&63; a = mw1[(10+2*q)*64 + hh]; c = mw1[(11+2*q)*64 + hh]; }
        else if (i < 736)  { j = i-640;  int r = j>>5, hp = j&31; a = mw1[(20+r)*64 + 2*hp]; c = mw1[(20+r)*64 + 2*hp+1]; }
        else if (i < 1056) { j = i-736;  int cc = j>>5, hp = j&31; a = mw2[(2*hp)*10 + cc];  c = mw2[(2*hp+1)*10 + cc]; }
        else if (i < 1088) { j = i-1056; a = ub1[2*j]; c = ub1[2*j+1]; }
        else if (i < 1728) { j = i-1088; int cc = j>>5, hp = j&31; a = uw1[cc*64 + 2*hp];    c = uw1[cc*64 + 2*hp+1]; }
        else               { j = i-1728; int cc = j>>5, hp = j&31; a = uw2[(2*hp)*10 + cc];  c = uw2[(2*hp+1)*10 + cc]; }
        wh[WS_W + i] = pkrtz(a, c);
    }
    if (b == 0 && t < 40) {
        float v;
        if      (t < 10) v = mb2[t];
        else if (t < 20) v = ub2[t-10];
        else if (t < 30) v = gam[t-20];
        else             v = bet[t-30];
        ((float*)ws)[WS_SCAL + t] = v;
    }
}

// ---------- main fused kernel ----------
// R6 structure (best measured: bench 295): 256 threads, 2 time-phases of
// 16 hp, nbp chunk-major [4][NPIX][4 u32] = 20736 B recycled between halves
// -> 7 blocks/CU LDS ceiling. Staging beliefs live in registers (bcA/bcB),
// loaded once. Change vs R6: __launch_bounds__(256, 5) -- the (,6) bound made
// the allocator squeeze to 40 VGPR and spill 32 B/thread (measured: WRITE_SIZE
// 73.7 MB vs 41 MB output, FETCH +14 MB). (,5) relaxes the cap (R3 analog:
// 44 VGPR, no spill); VGPR <= 73 keeps the full 7-block LDS occupancy.
__global__ __launch_bounds__(256, 5) void mp_kernel(
    const float* __restrict__ beliefs, const float* __restrict__ cons,
    const u32* __restrict__ ws, float* __restrict__ out)
{
    __shared__ __align__(16) u32 nbp_u[4*NPIX*4];   // 20736 B, [chunk][pixel][4]

    const int tid = threadIdx.x;
    const int b = blockIdx.z, y0 = blockIdx.y*TILE, x0 = blockIdx.x*TILE;

    const h2* Wfnb = (const h2*)ws;               // [64][32]
    const h2* W    = ((const h2*)ws) + WS_W;
    const float* SC = ((const float*)ws) + WS_SCAL;

    // ---- load staging pixels' beliefs ONCE into registers ----
    h2 bcA[5], bcB[5] = {};
    {
        const int p = tid;
        int py = p/HALO, px = p - py*HALO;
        int gy = y0-1+py; gy = gy<0?0:(gy>127?127:gy);
        int gx = x0-1+px; gx = gx<0?0:(gx>127?127:gx);
        const float2* bp = (const float2*)(beliefs + (size_t)((b*128+gy)*128+gx)*10);
        #pragma unroll
        for (int q = 0; q < 5; q++) { float2 v = bp[q]; bcA[q] = pkrtz(v.x, v.y); }
    }
    const bool hasB = tid < (NPIX - 256);   // tid < 68
    if (hasB) {
        const int p = tid + 256;
        int py = p/HALO, px = p - py*HALO;
        int gy = y0-1+py; gy = gy<0?0:(gy>127?127:gy);
        int gx = x0-1+px; gx = gx<0?0:(gx>127?127:gx);
        const float2* bp = (const float2*)(beliefs + (size_t)((b*128+gy)*128+gx)*10);
        #pragma unroll
        for (int q = 0; q < 5; q++) { float2 v = bp[q]; bcB[q] = pkrtz(v.x, v.y); }
    }

    // ---- per-pixel state ----
    const int tx = tid & 15, ty = tid >> 4;
    const int pc = (ty+1)*HALO + (tx+1);
    const size_t gpix = (size_t)((b*128 + (y0+ty))*128 + (x0+tx));

    u32 kb[8];   // byte bases of the 8 neighbors' nbp rows
    {
        const int doff[8] = {-19,-18,-17,-1,1,17,18,19};
        #pragma unroll
        for (int k = 0; k < 8; k++) kb[k] = (u32)(pc + doff[k]) * 16u;
    }

    float bel[10]; h2 beld[10];
    {
        const float2* bp = (const float2*)(beliefs + gpix*10);
        #pragma unroll
        for (int q = 0; q < 5; q++) {
            float2 v = bp[q];
            bel[2*q] = v.x; bel[2*q+1] = v.y;
            beld[2*q]   = pkrtz(v.x, v.x);
            beld[2*q+1] = pkrtz(v.y, v.y);
        }
    }
    h2 cond[24];
    {
        const float4* cp = (const float4*)(cons + gpix*24);
        #pragma unroll
        for (int r = 0; r < 6; r++) {
            float4 v = cp[r];
            cond[4*r+0] = pkrtz(v.x, v.x);
            cond[4*r+1] = pkrtz(v.y, v.y);
            cond[4*r+2] = pkrtz(v.z, v.z);
            cond[4*r+3] = pkrtz(v.w, v.w);
        }
    }

    float acc2[10];
    #pragma unroll
    for (int c = 0; c < 10; c++) acc2[c] = 0.f;

    char* nbpB = (char*)nbp_u;

    #pragma unroll
    for (int half = 0; half < 2; half++) {
        if (half) __syncthreads();   // all reads of previous half's nbp done

        // ---- nbp[cl][p] = bel[p] @ mw1[10:20] for hp in [half*16, +16), from regs ----
        #pragma unroll
        for (int cl = 0; cl < 4; cl++) {
            uint4 ov;
            u32 t[4];
            #pragma unroll
            for (int j = 0; j < 4; j++) {
                const int hp = half*16 + cl*4 + j;   // literal
                float a0 = 0.f, a1 = 0.f;
                #pragma unroll
                for (int q = 0; q < 5; q++) {
                    a0 = dot2f(bcA[q], W[W_NBW + q*64 + 2*hp],     a0);
                    a1 = dot2f(bcA[q], W[W_NBW + q*64 + 2*hp + 1], a1);
                }
                t[j] = __builtin_bit_cast(u32, pkrtz(a0, a1));
            }
            ov.x = t[0]; ov.y = t[1]; ov.z = t[2]; ov.w = t[3];
            *(uint4*)(nbpB + (u32)tid*16u + cl*(NPIX*16)) = ov;
        }
        if (hasB) {
            #pragma unroll
            for (int cl = 0; cl < 4; cl++) {
                uint4 ov;
                u32 t[4];
                #pragma unroll
                for (int j = 0; j < 4; j++) {
                    const int hp = half*16 + cl*4 + j;
                    float a0 = 0.f, a1 = 0.f;
                    #pragma unroll
                    for (int q = 0; q < 5; q++) {
                        a0 = dot2f(bcB[q], W[W_NBW + q*64 + 2*hp],     a0);
                        a1 = dot2f(bcB[q], W[W_NBW + q*64 + 2*hp + 1], a1);
                    }
                    t[j] = __builtin_bit_cast(u32, pkrtz(a0, a1));
                }
                ov.x = t[0]; ov.y = t[1]; ov.z = t[2]; ov.w = t[3];
                *(uint4*)(nbpB + (u32)(tid + 256)*16u + cl*(NPIX*16)) = ov;
            }
        }
        __syncthreads();   // nbp ready

        // ---- message net for this half's 4 chunks ----
        #pragma unroll 2
        for (int cl = 0; cl < 4; cl++) {
            const int hb = half*16 + cl*4;   // literal
            h2 t01[4], s01[4];
            #pragma unroll
            for (int j = 0; j < 4; j++) { t01[j] = Wfnb[b*32 + hb + j]; s01[j] = (h2)(_Float16)0; }
            #pragma unroll
            for (int c = 0; c < 10; c++) {
                #pragma unroll
                for (int j = 0; j < 4; j++)
                    t01[j] = pkfma(beld[c], W[W_SELF + c*32 + hb + j], t01[j]);
            }
            h2 wc0[4], wc1[4], wc2[4];
            #pragma unroll
            for (int j = 0; j < 4; j++) {
                wc0[j] = W[W_WC      + hb + j];
                wc1[j] = W[W_WC + 32 + hb + j];
                wc2[j] = W[W_WC + 64 + hb + j];
            }
            #pragma unroll
            for (int k = 0; k < 8; k++) {
                const uint4 nv = *(const uint4*)(nbpB + kb[k] + cl*(NPIX*16));
                const h2 nb[4] = { h2cast(nv.x), h2cast(nv.y), h2cast(nv.z), h2cast(nv.w) };
                const h2 c0 = cond[k*3+0], c1 = cond[k*3+1], c2 = cond[k*3+2];
                #pragma unroll
                for (int j = 0; j < 4; j++) {
                    h2 v = t01[j] + nb[j];
                    v = pkfma(c0, wc0[j], v);
                    v = pkfma(c1, wc1[j], v);
                    v = pkfma(c2, wc2[j], v);
                    s01[j] += relu2(v);
                }
            }
            #pragma unroll
            for (int c = 0; c < 10; c++) {
                #pragma unroll
                for (int j = 0; j < 4; j++)
                    acc2[c] = dot2f(s01[j], W[W_MW2 + c*32 + hb + j], acc2[c]);
            }
        }
    }

    // agg = mean + mb2, duplicated-f16
    h2 aggd[10];
    #pragma unroll
    for (int c = 0; c < 10; c++) {
        float a = acc2[c]*0.125f + SC[c];
        aggd[c] = pkrtz(a, a);
    }

    float od[10];
    #pragma unroll
    for (int c = 0; c < 10; c++) od[c] = 0.f;

    #pragma unroll 4
    for (int hp = 0; hp < 32; hp++) {
        h2 u01 = W[W_UB1 + hp];
        #pragma unroll
        for (int c = 0; c < 10; c++) u01 = pkfma(beld[c], W[W_UW1 + c*32 + hp], u01);
        #pragma unroll
        for (int c = 0; c < 10; c++) u01 = pkfma(aggd[c], W[W_UW1 + (10+c)*32 + hp], u01);
        u01 = relu2(u01);
        #pragma unroll
        for (int c = 0; c < 10; c++) od[c] = dot2f(u01, W[W_UW2 + c*32 + hp], od[c]);
    }

    float x[10], mu = 0.f;
    #pragma unroll
    for (int c = 0; c < 10; c++) { x[c] = bel[c] + 0.5f*(od[c] + SC[10+c]); mu += x[c]; }
    mu *= 0.1f;
    float var = 0.f;
    #pragma unroll
    for (int c = 0; c < 10; c++) { float d = x[c] - mu; var += d*d; }
    var *= 0.1f;
    const float rs = rsqrtf(var + 1e-5f);

    float2* op = (float2*)(out + gpix*10);
    #pragma unroll
    for (int q = 0; q < 5; q++) {
        float2 r;
        r.x = (x[2*q]   - mu)*rs*SC[20+2*q]   + SC[30+2*q];
        r.y = (x[2*q+1] - mu)*rs*SC[20+2*q+1] + SC[30+2*q+1];
        op[q] = r;
    }
}

// ================== fallback (proven kernel, fp32 inputs) ==================
__device__ __forceinline__ float bf_lo(u32 v) { return __uint_as_float(v << 16); }
__device__ __forceinline__ float bf_hi(u32 v) { return __uint_as_float(v & 0xffff0000u); }
__device__ __forceinline__ u32 f2bf(float f) {
    u32 u = __float_as_uint(f);
    return (u + 0x7fffu + ((u >> 16) & 1u)) >> 16;
}
__device__ __forceinline__ u32 pack2(float a, float b) { return f2bf(a) | (f2bf(b) << 16); }
__device__ __forceinline__ u32 fpair(const float* a, int pi) { return pack2(a[2*pi], a[2*pi+1]); }

#define FW_MW2 736
#define FW_MB2 1056
#define FW_UW1 1061
#define FW_UB1 1701
#define FW_UW2 1733
#define FW_UB2 2053
#define FW_GAM 2058
#define FW_BET 2063
#define FW_TOT 2068

__global__ __launch_bounds__(256) void fallback_kernel(
    const float* __restrict__ beliefs, const float* __restrict__ cons, const float* __restrict__ fn,
    const float* __restrict__ mw1, const float* __restrict__ mb1, const float* __restrict__ mw2,
    const float* __restrict__ mb2, const float* __restrict__ uw1, const float* __restrict__ ub1,
    const float* __restrict__ uw2, const float* __restrict__ ub2, const float* __restrict__ gam,
    const float* __restrict__ bet, float* __restrict__ out)
{
    __shared__ float bel_s[NPIX*10];
    __shared__ u32   nbp_s[32*NPIX];
    __shared__ u32   w_s[FW_TOT];
    __shared__ float fnb_s[64];

    const int tid = threadIdx.x;
    const int b  = blockIdx.z;
    const int y0 = blockIdx.y * TILE;
    const int x0 = blockIdx.x * TILE;

    for (int i = tid; i < FW_TOT; i += 256) {
        u32 v;
        if      (i < 736)  v = fpair(mw1, i);
        else if (i < 1056) v = fpair(mw2, i - 736);
        else if (i < 1061) v = fpair(mb2, i - 1056);
        else if (i < 1701) v = fpair(uw1, i - 1061);
        else if (i < 1733) v = fpair(ub1, i - 1701);
        else if (i < 2053) v = fpair(uw2, i - 1733);
        else if (i < 2058) v = fpair(ub2, i - 2053);
        else if (i < 2063) v = fpair(gam, i - 2058);
        else               v = fpair(bet, i - 2063);
        w_s[i] = v;
    }
    if (tid < 64) {
        float acc = mb1[tid];
        #pragma unroll 8
        for (int f = 0; f < 32; f++)
            acc += fn[b*32 + f] * mw1[(23 + f)*64 + tid];
        fnb_s[tid] = acc;
    }
    for (int idx = tid; idx < NPIX*10; idx += 256) {
        int p = idx/10, c = idx - p*10;
        int py = p/HALO, px = p - py*HALO;
        int gy = y0-1+py; gy = gy<0?0:(gy>127?127:gy);
        int gx = x0-1+px; gx = gx<0?0:(gx>127?127:gx);
        bel_s[idx] = beliefs[((size_t)(b*128+gy)*128+gx)*10 + c];
    }
    __syncthreads();

    for (int p = tid; p < NPIX; p += 256) {
        float bl[10];
        #pragma unroll
        for (int c = 0; c < 10; c++) bl[c] = bel_s[p*10 + c];
        #pragma unroll 4
        for (int hp = 0; hp < 32; hp++) {
            float t0 = 0.f, t1 = 0.f;
            #pragma unroll
            for (int c = 0; c < 10; c++) {
                u32 wv = w_s[(10 + c)*32 + hp];
                t0 += bl[c] * bf_lo(wv);
                t1 += bl[c] * bf_hi(wv);
            }
            nbp_s[hp*NPIX + p] = pack2(t0, t1);
        }
    }
    __syncthreads();

    const int tx = tid & 15, ty = tid >> 4;
    const int pc = (ty + 1)*HALO + (tx + 1);
    float bel[10];
    #pragma unroll
    for (int c = 0; c < 10; c++) bel[c] = bel_s[pc*10 + c];
    const size_t gpix = (size_t)(b*128 + (y0 + ty))*128 + (x0 + tx);
    float con[24];
    #pragma unroll
    for (int j = 0; j < 24; j++) con[j] = cons[gpix*24 + j];

    float acc2[10];
    #pragma unroll
    for (int c = 0; c < 10; c++) acc2[c] = 0.f;

    #pragma unroll 2
    for (int hp = 0; hp < 32; hp++) {
        const int h0 = 2*hp, h1 = h0 + 1;
        float t0 = fnb_s[h0], t1 = fnb_s[h1];
        #pragma unroll
        for (int c = 0; c < 10; c++) {
            u32 wv = w_s[c*32 + hp];
            t0 += bel[c] * bf_lo(wv);
            t1 += bel[c] * bf_hi(wv);
        }
        const u32 wc0 = w_s[20*32 + hp], wc1 = w_s[21*32 + hp], wc2 = w_s[22*32 + hp];
        const u32* nbb = nbp_s + hp*NPIX + pc - 19;
        float s0 = 0.f, s1 = 0.f;
        #pragma unroll
        for (int k = 0; k < 8; k++) {
            const int doff[8] = { 0, 1, 2, 18, 20, 36, 37, 38 };
            u32 nv = nbb[doff[k]];
            float c0 = con[k*3], c1 = con[k*3+1], c2 = con[k*3+2];
            float v0 = t0 + bf_lo(nv) + c0*bf_lo(wc0) + c1*bf_lo(wc1) + c2*bf_lo(wc2);
            float v1 = t1 + bf_hi(nv) + c0*bf_hi(wc0) + c1*bf_hi(wc1) + c2*bf_hi(wc2);
            s0 += fmaxf(v0, 0.f);
            s1 += fmaxf(v1, 0.f);
        }
        #pragma unroll
        for (int cq = 0; cq < 5; cq++) {
            u32 a0 = w_s[FW_MW2 + h0*5 + cq];
            u32 a1 = w_s[FW_MW2 + h1*5 + cq];
            acc2[2*cq]   += s0*bf_lo(a0) + s1*bf_lo(a1);
            acc2[2*cq+1] += s0*bf_hi(a0) + s1*bf_hi(a1);
        }
    }

    float agg[10];
    #pragma unroll
    for (int cq = 0; cq < 5; cq++) {
        u32 bp = w_s[FW_MB2 + cq];
        agg[2*cq]   = acc2[2*cq]  *0.125f + bf_lo(bp);
        agg[2*cq+1] = acc2[2*cq+1]*0.125f + bf_hi(bp);
    }

    float od[10];
    #pragma unroll
    for (int c = 0; c < 10; c++) od[c] = 0.f;
    #pragma unroll 2
    for (int hp = 0; hp < 32; hp++) {
        u32 ubp = w_s[FW_UB1 + hp];
        float u0 = bf_lo(ubp), u1 = bf_hi(ubp);
        #pragma unroll
        for (int c = 0; c < 10; c++) {
            u32 wv = w_s[FW_UW1 + c*32 + hp];
            u0 += bel[c] * bf_lo(wv);
            u1 += bel[c] * bf_hi(wv);
        }
        #pragma unroll
        for (int c = 0; c < 10; c++) {
            u32 wv = w_s[FW_UW1 + (10 + c)*32 + hp];
            u0 += agg[c] * bf_lo(wv);
            u1 += agg[c] * bf_hi(wv);
        }
        u0 = fmaxf(u0, 0.f); u1 = fmaxf(u1, 0.f);
        const int h0 = 2*hp, h1 = h0 + 1;
        #pragma unroll
        for (int cq = 0; cq < 5; cq++) {
            u32 a0 = w_s[FW_UW2 + h0*5 + cq];
            u32 a1 = w_s[FW_UW2 + h1*5 + cq];
            od[2*cq]   += u0*bf_lo(a0) + u1*bf_lo(a1);
            od[2*cq+1] += u0*bf_hi(a0) + u1*bf_hi(a1);
        }
    }

    float x[10], mu = 0.f;
    #pragma unroll
    for (int cq = 0; cq < 5; cq++) {
        u32 bp = w_s[FW_UB2 + cq];
        x[2*cq]   = bel[2*cq]   + 0.5f*(od[2*cq]   + bf_lo(bp));
        x[2*cq+1] = bel[2*cq+1] + 0.5f*(od[2*cq+1] + bf_hi(bp));
        mu += x[2*cq] + x[2*cq+1];
    }
    mu *= 0.1f;
    float var = 0.f;
    #pragma unroll
    for (int c = 0; c < 10; c++) { float d = x[c] - mu; var += d*d; }
    var *= 0.1f;
    const float rs = rsqrtf(var + 1e-5f);

    float2* op = reinterpret_cast<float2*>(out + gpix*10);
    #pragma unroll
    for (int q = 0; q < 5; q++) {
        u32 gp = w_s[FW_GAM + q], bq = w_s[FW_BET + q];
        float2 r;
        r.x = (x[2*q]   - mu)*rs*bf_lo(gp) + bf_lo(bq);
        r.y = (x[2*q+1] - mu)*rs*bf_hi(gp) + bf_hi(bq);
        op[q] = r;
    }
}

extern "C" void kernel_launch(void* const* d_in, const int* in_sizes, int n_in,
                              void* d_out, int out_size, void* d_ws, size_t ws_size,
                              hipStream_t stream) {
    (void)in_sizes; (void)n_in; (void)out_size;
    const float* beliefs = (const float*)d_in[0];
    const float* cons    = (const float*)d_in[1];
    const float* fn      = (const float*)d_in[2];
    const float* mw1     = (const float*)d_in[3];
    const float* mb1     = (const float*)d_in[4];
    const float* mw2     = (const float*)d_in[5];
    const float* mb2     = (const float*)d_in[6];
    const float* uw1     = (const float*)d_in[7];
    const float* ub1     = (const float*)d_in[8];
    const float* uw2     = (const float*)d_in[9];
    const float* ub2     = (const float*)d_in[10];
    const float* gam     = (const float*)d_in[11];
    const float* bet     = (const float*)d_in[12];
    float* outp = (float*)d_out;

    if (ws_size >= (size_t)WS_DWORDS*4) {
        prep_kernel<<<dim3(64), dim3(64), 0, stream>>>(
            fn, mw1, mb1, mw2, mb2, uw1, ub1, uw2, ub2, gam, bet, (u32*)d_ws);
        mp_kernel<<<dim3(8, 8, 64), dim3(256), 0, stream>>>(
            beliefs, cons, (const u32*)d_ws, outp);
    } else {
        fallback_kernel<<<dim3(8, 8, 64), dim3(256), 0, stream>>>(
            beliefs, cons, fn, mw1, mb1, mw2, mb2, uw1, ub1, uw2, ub2, gam, bet, outp);
    }
}